// Round 1
// 82.212 us; speedup vs baseline: 1.1038x; 1.1038x over previous
//
#include <hip/hip_runtime.h>

#define Bn 2
#define Nn 4096
#define Cn 256
#define Kn 64
#define BK (Bn * Kn)
#define NW 16            // waves per block
#define BT 1024          // threads per block

__device__ __forceinline__ float4 max4(float4 a, float4 b) {
    return make_float4(fmaxf(a.x, b.x), fmaxf(a.y, b.y),
                       fmaxf(a.z, b.z), fmaxf(a.w, b.w));
}

// One block per (b,k) box: scan -> compact -> wave-row float4 gather-max ->
// cross-wave reduce -> 2-layer MLP (c-split 4 ways), all in one launch.
__global__ __launch_bounds__(BT) void fused_roi_kernel(
    const float* __restrict__ points,      // (B,N,3)
    const float* __restrict__ feats,       // (B,N,C)
    const float* __restrict__ proposals,   // (B,K,7)
    const float* __restrict__ W1,          // (C,256)
    const float* __restrict__ b1,
    const float* __restrict__ W2,          // (256,256)
    const float* __restrict__ b2,
    float* __restrict__ out)               // (B,K,256)
{
    const int bk   = blockIdx.x;
    const int b    = bk / Kn;
    const int tid  = threadIdx.x;
    const int w    = tid >> 6;             // wave id 0..15
    const int lane = tid & 63;

    __shared__ int   s_idx[Nn];            // 16 KB
    __shared__ int   s_count;
    __shared__ float s_part[NW][Cn];       // 16 KB
    __shared__ float s_vec[Cn];            // 1 KB
    __shared__ float s_red[4][Cn];         // 4 KB

    // ---- box bounds ----
    const float* prop = proposals + (size_t)bk * 7;
    const float cx = prop[0], cy = prop[1], cz = prop[2];
    const float hx = prop[3] * 0.5f, hy = prop[4] * 0.5f, hz = prop[5] * 0.5f;
    const float lox = cx - hx, loy = cy - hy, loz = cz - hz;
    const float hix = cx + hx, hiy = cy + hy, hiz = cz + hz;

    if (tid == 0) s_count = 0;
    __syncthreads();

    // ---- phase 1: scan all N points, compact inside-indices to LDS ----
    const float* pts = points + (size_t)b * Nn * 3;
    #pragma unroll
    for (int n = tid; n < Nn; n += BT) {
        const float px = pts[n * 3 + 0];
        const float py = pts[n * 3 + 1];
        const float pz = pts[n * 3 + 2];
        const bool in = (px > lox) & (px < hix) &
                        (py > loy) & (py < hiy) &
                        (pz > loz) & (pz < hiz);
        if (in) {
            const int pos = atomicAdd(&s_count, 1);
            s_idx[pos] = n;
        }
    }
    __syncthreads();
    const int count = s_count;

    // ---- phase 2: gather-max. wave w owns rows w, w+16, ... ----
    // lane l covers channels [4l, 4l+4): one full 1KB row per wave-instruction.
    const float* fb = feats + (size_t)b * Nn * Cn;
    float4 mx = make_float4(-INFINITY, -INFINITY, -INFINITY, -INFINITY);
    int i = w;
    // 8-deep batches: 8 independent index reads -> 8 independent 16B loads
    for (; i + 7 * NW < count; i += 8 * NW) {
        const int a0 = s_idx[i + 0 * NW], a1 = s_idx[i + 1 * NW];
        const int a2 = s_idx[i + 2 * NW], a3 = s_idx[i + 3 * NW];
        const int a4 = s_idx[i + 4 * NW], a5 = s_idx[i + 5 * NW];
        const int a6 = s_idx[i + 6 * NW], a7 = s_idx[i + 7 * NW];
        const float4 f0 = *(const float4*)(fb + (size_t)a0 * Cn + lane * 4);
        const float4 f1 = *(const float4*)(fb + (size_t)a1 * Cn + lane * 4);
        const float4 f2 = *(const float4*)(fb + (size_t)a2 * Cn + lane * 4);
        const float4 f3 = *(const float4*)(fb + (size_t)a3 * Cn + lane * 4);
        const float4 f4 = *(const float4*)(fb + (size_t)a4 * Cn + lane * 4);
        const float4 f5 = *(const float4*)(fb + (size_t)a5 * Cn + lane * 4);
        const float4 f6 = *(const float4*)(fb + (size_t)a6 * Cn + lane * 4);
        const float4 f7 = *(const float4*)(fb + (size_t)a7 * Cn + lane * 4);
        mx = max4(mx, max4(max4(f0, f1), max4(f2, f3)));
        mx = max4(mx, max4(max4(f4, f5), max4(f6, f7)));
    }
    for (; i < count; i += NW) {
        const int a = s_idx[i];
        mx = max4(mx, *(const float4*)(fb + (size_t)a * Cn + lane * 4));
    }
    *(float4*)&s_part[w][lane * 4] = mx;
    __syncthreads();

    // ---- phase 3: reduce 16 wave-partials, empty box -> 0 ----
    if (tid < Cn) {
        float m = s_part[0][tid];
        #pragma unroll
        for (int k = 1; k < NW; ++k) m = fmaxf(m, s_part[k][tid]);
        if (m == -INFINITY) m = 0.0f;
        s_vec[tid] = m;
    }
    __syncthreads();

    // ---- phase 4: layer 1, c-split 4 ways (chain length 64) ----
    {
        const int g = tid >> 8;            // 0..3
        const int d = tid & 255;
        const float* w1 = W1 + (size_t)(g * 64) * 256 + d;
        const float* sv = s_vec + g * 64;
        float acc = 0.0f;
        #pragma unroll 16
        for (int c = 0; c < 64; ++c) {
            acc = fmaf(sv[c], w1[(size_t)c * 256], acc);
        }
        s_red[g][d] = acc;
    }
    __syncthreads();
    if (tid < Cn) {
        const float h = fmaxf(
            b1[tid] + ((s_red[0][tid] + s_red[1][tid]) +
                       (s_red[2][tid] + s_red[3][tid])), 0.0f);
        s_vec[tid] = h;
    }
    __syncthreads();

    // ---- phase 5: layer 2, same split ----
    {
        const int g = tid >> 8;
        const int d = tid & 255;
        const float* w2 = W2 + (size_t)(g * 64) * 256 + d;
        const float* sv = s_vec + g * 64;
        float acc = 0.0f;
        #pragma unroll 16
        for (int c = 0; c < 64; ++c) {
            acc = fmaf(sv[c], w2[(size_t)c * 256], acc);
        }
        s_red[g][d] = acc;
    }
    __syncthreads();
    if (tid < Cn) {
        out[(size_t)bk * 256 + tid] = fmaxf(
            b2[tid] + ((s_red[0][tid] + s_red[1][tid]) +
                       (s_red[2][tid] + s_red[3][tid])), 0.0f);
    }
}

extern "C" void kernel_launch(void* const* d_in, const int* in_sizes, int n_in,
                              void* d_out, int out_size, void* d_ws, size_t ws_size,
                              hipStream_t stream) {
    const float* points    = (const float*)d_in[0];
    const float* feats     = (const float*)d_in[1];
    const float* proposals = (const float*)d_in[2];
    const float* W1        = (const float*)d_in[3];
    const float* b1        = (const float*)d_in[4];
    const float* W2        = (const float*)d_in[5];
    const float* b2        = (const float*)d_in[6];
    float* out             = (float*)d_out;
    (void)d_ws; (void)ws_size;

    fused_roi_kernel<<<BK, BT, 0, stream>>>(points, feats, proposals,
                                            W1, b1, W2, b2, out);
}

// Round 2
// 80.717 us; speedup vs baseline: 1.1242x; 1.0185x over previous
//
#include <hip/hip_runtime.h>

#define Bn 2
#define Nn 4096
#define Cn 256
#define Kn 64
#define BK (Bn * Kn)
#define NW 16            // waves per block
#define BT 1024          // threads per block
#define PAD (7 * NW)     // gather batch over-read padding

__device__ __forceinline__ float4 max4(float4 a, float4 b) {
    return make_float4(fmaxf(a.x, b.x), fmaxf(a.y, b.y),
                       fmaxf(a.z, b.z), fmaxf(a.w, b.w));
}

// One block per (b,k) box: float4 scan -> compact(+pad) -> wave-row float4
// gather-max (always full 8-deep batches) -> cross-wave reduce -> 2-layer MLP.
__global__ __launch_bounds__(BT) void fused_roi_kernel(
    const float* __restrict__ points,      // (B,N,3)
    const float* __restrict__ feats,       // (B,N,C)
    const float* __restrict__ proposals,   // (B,K,7)
    const float* __restrict__ W1,          // (C,256)
    const float* __restrict__ b1,
    const float* __restrict__ W2,          // (256,256)
    const float* __restrict__ b2,
    float* __restrict__ out)               // (B,K,256)
{
    const int bk   = blockIdx.x;
    const int b    = bk / Kn;
    const int tid  = threadIdx.x;
    const int w    = tid >> 6;             // wave id 0..15
    const int lane = tid & 63;

    __shared__ int   s_idx[Nn + PAD];      // 16.4 KB
    __shared__ int   s_count;
    __shared__ float s_part[NW][Cn];       // 16 KB
    __shared__ float s_vec[Cn];            // 1 KB
    __shared__ float s_red[4][Cn];         // 4 KB

    // ---- box bounds ----
    const float* prop = proposals + (size_t)bk * 7;
    const float cx = prop[0], cy = prop[1], cz = prop[2];
    const float hx = prop[3] * 0.5f, hy = prop[4] * 0.5f, hz = prop[5] * 0.5f;
    const float lox = cx - hx, loy = cy - hy, loz = cz - hz;
    const float hix = cx + hx, hiy = cy + hy, hiz = cz + hz;

    if (tid == 0) s_count = 0;
    __syncthreads();

    // ---- phase 1: scan. thread t owns points 4t..4t+3 via 3 float4 loads ----
    {
        const float4* pv = (const float4*)(points + (size_t)b * Nn * 3);
        const float4 q0 = pv[3 * tid + 0];   // x0 y0 z0 x1
        const float4 q1 = pv[3 * tid + 1];   // y1 z1 x2 y2
        const float4 q2 = pv[3 * tid + 2];   // z2 x3 y3 z3
        const int n0 = 4 * tid;

        const bool in0 = (q0.x > lox) & (q0.x < hix) &
                         (q0.y > loy) & (q0.y < hiy) &
                         (q0.z > loz) & (q0.z < hiz);
        const bool in1 = (q0.w > lox) & (q0.w < hix) &
                         (q1.x > loy) & (q1.x < hiy) &
                         (q1.y > loz) & (q1.y < hiz);
        const bool in2 = (q1.z > lox) & (q1.z < hix) &
                         (q1.w > loy) & (q1.w < hiy) &
                         (q2.x > loz) & (q2.x < hiz);
        const bool in3 = (q2.y > lox) & (q2.y < hix) &
                         (q2.z > loy) & (q2.z < hiy) &
                         (q2.w > loz) & (q2.w < hiz);

        if (in0) s_idx[atomicAdd(&s_count, 1)] = n0 + 0;
        if (in1) s_idx[atomicAdd(&s_count, 1)] = n0 + 1;
        if (in2) s_idx[atomicAdd(&s_count, 1)] = n0 + 2;
        if (in3) s_idx[atomicAdd(&s_count, 1)] = n0 + 3;
    }
    __syncthreads();
    const int count = s_count;

    // pad so the gather can always run full 8-deep batches (dupes are
    // harmless under max)
    if (count > 0 && tid < PAD) s_idx[count + tid] = s_idx[0];
    __syncthreads();

    // ---- phase 2: gather-max. wave w owns rows w, w+16, ...; lane l covers
    // channels [4l,4l+4) -> one full 1KB row per wave-instruction ----
    const float* fb = feats + (size_t)b * Nn * Cn;
    float4 mx = make_float4(-INFINITY, -INFINITY, -INFINITY, -INFINITY);
    for (int i = w; i < count; i += 8 * NW) {
        const int a0 = s_idx[i + 0 * NW], a1 = s_idx[i + 1 * NW];
        const int a2 = s_idx[i + 2 * NW], a3 = s_idx[i + 3 * NW];
        const int a4 = s_idx[i + 4 * NW], a5 = s_idx[i + 5 * NW];
        const int a6 = s_idx[i + 6 * NW], a7 = s_idx[i + 7 * NW];
        const float4 f0 = *(const float4*)(fb + (size_t)a0 * Cn + lane * 4);
        const float4 f1 = *(const float4*)(fb + (size_t)a1 * Cn + lane * 4);
        const float4 f2 = *(const float4*)(fb + (size_t)a2 * Cn + lane * 4);
        const float4 f3 = *(const float4*)(fb + (size_t)a3 * Cn + lane * 4);
        const float4 f4 = *(const float4*)(fb + (size_t)a4 * Cn + lane * 4);
        const float4 f5 = *(const float4*)(fb + (size_t)a5 * Cn + lane * 4);
        const float4 f6 = *(const float4*)(fb + (size_t)a6 * Cn + lane * 4);
        const float4 f7 = *(const float4*)(fb + (size_t)a7 * Cn + lane * 4);
        mx = max4(mx, max4(max4(f0, f1), max4(f2, f3)));
        mx = max4(mx, max4(max4(f4, f5), max4(f6, f7)));
    }
    *(float4*)&s_part[w][lane * 4] = mx;
    __syncthreads();

    // ---- phase 3: reduce 16 wave-partials, empty box -> 0 ----
    if (tid < Cn) {
        float m = s_part[0][tid];
        #pragma unroll
        for (int k = 1; k < NW; ++k) m = fmaxf(m, s_part[k][tid]);
        if (m == -INFINITY) m = 0.0f;
        s_vec[tid] = m;
    }
    __syncthreads();

    // ---- phase 4: layer 1, c-split 4 ways (chain length 64) ----
    {
        const int g = tid >> 8;            // 0..3
        const int d = tid & 255;
        const float* w1 = W1 + (size_t)(g * 64) * 256 + d;
        const float* sv = s_vec + g * 64;
        float acc = 0.0f;
        #pragma unroll 16
        for (int c = 0; c < 64; ++c) {
            acc = fmaf(sv[c], w1[(size_t)c * 256], acc);
        }
        s_red[g][d] = acc;
    }
    __syncthreads();
    if (tid < Cn) {
        const float h = fmaxf(
            b1[tid] + ((s_red[0][tid] + s_red[1][tid]) +
                       (s_red[2][tid] + s_red[3][tid])), 0.0f);
        s_vec[tid] = h;
    }
    __syncthreads();

    // ---- phase 5: layer 2, same split ----
    {
        const int g = tid >> 8;
        const int d = tid & 255;
        const float* w2 = W2 + (size_t)(g * 64) * 256 + d;
        const float* sv = s_vec + g * 64;
        float acc = 0.0f;
        #pragma unroll 16
        for (int c = 0; c < 64; ++c) {
            acc = fmaf(sv[c], w2[(size_t)c * 256], acc);
        }
        s_red[g][d] = acc;
    }
    __syncthreads();
    if (tid < Cn) {
        out[(size_t)bk * 256 + tid] = fmaxf(
            b2[tid] + ((s_red[0][tid] + s_red[1][tid]) +
                       (s_red[2][tid] + s_red[3][tid])), 0.0f);
    }
}

extern "C" void kernel_launch(void* const* d_in, const int* in_sizes, int n_in,
                              void* d_out, int out_size, void* d_ws, size_t ws_size,
                              hipStream_t stream) {
    const float* points    = (const float*)d_in[0];
    const float* feats     = (const float*)d_in[1];
    const float* proposals = (const float*)d_in[2];
    const float* W1        = (const float*)d_in[3];
    const float* b1        = (const float*)d_in[4];
    const float* W2        = (const float*)d_in[5];
    const float* b2        = (const float*)d_in[6];
    float* out             = (float*)d_out;
    (void)d_ws; (void)ws_size;

    fused_roi_kernel<<<BK, BT, 0, stream>>>(points, feats, proposals,
                                            W1, b1, W2, b2, out);
}